// Round 2
// baseline (12.850 us; speedup 1.0000x reference)
//
#include <hip/hip_runtime.h>
#include <math.h>

#define NH 32
#define NL 8
#define NF 128

// Scheduling fence only: no s_barrier, no forced vmcnt(0) drain. Single-wave
// block => cross-lane LDS handoff is ordered by per-wave in-order DS pipe +
// compiler-inserted lgkmcnt; this fence stops compiler reordering across it.
#define WSYNC() __builtin_amdgcn_wave_barrier()

template <int N4>
__device__ __forceinline__ float dotN(const float* __restrict__ w,
                                      const float* __restrict__ s) {
    const float4* w4 = (const float4*)w;
    float a0 = 0.f, a1 = 0.f, a2 = 0.f, a3 = 0.f;
#pragma unroll
    for (int i = 0; i < N4; ++i) {
        float4 a = w4[i];
        a0 = fmaf(a.x, s[4 * i + 0], a0);
        a1 = fmaf(a.y, s[4 * i + 1], a1);
        a2 = fmaf(a.z, s[4 * i + 2], a2);
        a3 = fmaf(a.w, s[4 * i + 3], a3);
    }
    return (a0 + a1) + (a2 + a3);
}

__device__ __forceinline__ float sigmoidf_(float x) {
    return 1.0f / (1.0f + __expf(-x));
}

__device__ __forceinline__ float tanhf_(float x) {
    // tanh(x) = 1 - 2/(e^{2x}+1); e->inf => 1, e->0 => -1. ~1e-7 rel err.
    float e = __expf(2.0f * x);
    return 1.0f - 2.0f / (e + 1.0f);
}

__device__ __forceinline__ float preluf_(float x, float a) {
    return x >= 0.0f ? x : a * x;
}

__global__ void __launch_bounds__(64)
omni_anomaly_kernel(const float* __restrict__ x,
                    const float* __restrict__ hidden,
                    const float* __restrict__ eps,
                    const float* __restrict__ w_ih0, const float* __restrict__ w_hh0,
                    const float* __restrict__ b_ih0, const float* __restrict__ b_hh0,
                    const float* __restrict__ w_ih1, const float* __restrict__ w_hh1,
                    const float* __restrict__ b_ih1, const float* __restrict__ b_hh1,
                    const float* __restrict__ enc_w1, const float* __restrict__ enc_b1,
                    const float* __restrict__ enc_a1,
                    const float* __restrict__ enc_w2, const float* __restrict__ enc_b2,
                    const float* __restrict__ enc_a2,
                    const float* __restrict__ enc_w3, const float* __restrict__ enc_b3,
                    const float* __restrict__ dec_w1, const float* __restrict__ dec_b1,
                    const float* __restrict__ dec_a1,
                    const float* __restrict__ dec_w2, const float* __restrict__ dec_b2,
                    const float* __restrict__ dec_a2,
                    const float* __restrict__ dec_w3, const float* __restrict__ dec_b3,
                    float* __restrict__ out) {
    __shared__ __align__(16) float sx[NF];
    __shared__ __align__(16) float sh0[NH];
    __shared__ __align__(16) float sh1[NH];
    __shared__ __align__(16) float gi0[3 * NH];
    __shared__ __align__(16) float gh0[3 * NH];
    __shared__ __align__(16) float gi1[3 * NH];
    __shared__ __align__(16) float gh1[3 * NH];
    __shared__ __align__(16) float h0n[NH];
    __shared__ __align__(16) float h1n[NH];
    __shared__ __align__(16) float e1b[NH];
    __shared__ __align__(16) float e2b[NH];
    __shared__ __align__(16) float eo[2 * NL];
    __shared__ __align__(16) float zb[NL];
    __shared__ __align__(16) float d1b[NH];
    __shared__ __align__(16) float d2b[NH];

    const int t = threadIdx.x;  // 0..63, one wave

    // ---- stage x, h0, h1 into LDS; keep h0/h1 rows in regs for combine ----
    float h0reg = 0.f, h1reg = 0.f;
    if (t < NF / 4) {  // 32 lanes x float4 = 128
        ((float4*)sx)[t] = ((const float4*)x)[t];
    }
    if (t < NH) {
        h0reg = hidden[t];
        h1reg = hidden[NH + t];
        sh0[t] = h0reg;
        sh1[t] = h1reg;
    }
    WSYNC();

    // ---- GRU0 matvecs: gi0 = w_ih0@x+b (96 rows of 128), gh0 = w_hh0@h0+b (96 rows of 32)
    // lanes 0..63: gi0 row t; lanes 0..31: gi0 row 64+t; lanes 32..63: gh0 rows 3(t-32)+{0,1,2}
    gi0[t] = dotN<NF / 4>(w_ih0 + t * NF, sx) + b_ih0[t];
    if (t < 32) {
        int r = 64 + t;
        gi0[r] = dotN<NF / 4>(w_ih0 + r * NF, sx) + b_ih0[r];
    } else {
        int r = 3 * (t - 32);
        gh0[r + 0] = dotN<NH / 4>(w_hh0 + (r + 0) * NH, sh0) + b_hh0[r + 0];
        gh0[r + 1] = dotN<NH / 4>(w_hh0 + (r + 1) * NH, sh0) + b_hh0[r + 1];
        gh0[r + 2] = dotN<NH / 4>(w_hh0 + (r + 2) * NH, sh0) + b_hh0[r + 2];
    }
    WSYNC();

    // ---- GRU0 combine ----
    if (t < NH) {
        float r = sigmoidf_(gi0[t] + gh0[t]);
        float z = sigmoidf_(gi0[NH + t] + gh0[NH + t]);
        float n = tanhf_(gi0[2 * NH + t] + r * gh0[2 * NH + t]);
        float h = (1.0f - z) * n + z * h0reg;
        h0n[t] = h;
        out[NF + 2 * NL + t] = h;  // hidden_new[0]
    }
    WSYNC();

    // ---- GRU1 matvecs: 192 dots of 32; lane t does dots t, t+64, t+128 ----
#pragma unroll
    for (int k = 0; k < 3; ++k) {
        int d = t + 64 * k;
        if (d < 3 * NH) {
            gi1[d] = dotN<NH / 4>(w_ih1 + d * NH, h0n) + b_ih1[d];
        } else {
            int r = d - 3 * NH;
            gh1[r] = dotN<NH / 4>(w_hh1 + r * NH, sh1) + b_hh1[r];
        }
    }
    WSYNC();

    // ---- GRU1 combine ----
    if (t < NH) {
        float r = sigmoidf_(gi1[t] + gh1[t]);
        float z = sigmoidf_(gi1[NH + t] + gh1[NH + t]);
        float n = tanhf_(gi1[2 * NH + t] + r * gh1[2 * NH + t]);
        float h = (1.0f - z) * n + z * h1reg;
        h1n[t] = h;
        out[NF + 2 * NL + NH + t] = h;  // hidden_new[1]
    }
    WSYNC();

    // ---- encoder 1 ----
    if (t < NH) {
        float v = dotN<NH / 4>(enc_w1 + t * NH, h1n) + enc_b1[t];
        e1b[t] = preluf_(v, enc_a1[0]);
    }
    WSYNC();

    // ---- encoder 2 ----
    if (t < NH) {
        float v = dotN<NH / 4>(enc_w2 + t * NH, e1b) + enc_b2[t];
        e2b[t] = preluf_(v, enc_a2[0]);
    }
    WSYNC();

    // ---- encoder 3: mu (0..7), logvar (8..15) ----
    if (t < 2 * NL) {
        float v = dotN<NH / 4>(enc_w3 + t * NH, e2b) + enc_b3[t];
        eo[t] = v;
        out[NF + t] = v;  // mu | logvar
    }
    WSYNC();

    // ---- reparameterize ----
    if (t < NL) {
        zb[t] = eo[t] + eps[t] * __expf(0.5f * eo[NL + t]);
    }
    WSYNC();

    // ---- decoder 1 (32 rows of 8) ----
    if (t < NH) {
        float v = dotN<NL / 4>(dec_w1 + t * NL, zb) + dec_b1[t];
        d1b[t] = preluf_(v, dec_a1[0]);
    }
    WSYNC();

    // ---- decoder 2 ----
    if (t < NH) {
        float v = dotN<NH / 4>(dec_w2 + t * NH, d1b) + dec_b2[t];
        d2b[t] = preluf_(v, dec_a2[0]);
    }
    WSYNC();

    // ---- decoder 3 (128 rows of 32): lane t -> rows t and 64+t ----
    {
        float v0 = dotN<NH / 4>(dec_w3 + t * NH, d2b) + dec_b3[t];
        out[t] = sigmoidf_(v0);
        int r = 64 + t;
        float v1 = dotN<NH / 4>(dec_w3 + r * NH, d2b) + dec_b3[r];
        out[r] = sigmoidf_(v1);
    }
}

extern "C" void kernel_launch(void* const* d_in, const int* in_sizes, int n_in,
                              void* d_out, int out_size, void* d_ws, size_t ws_size,
                              hipStream_t stream) {
    const float* x      = (const float*)d_in[0];
    const float* hidden = (const float*)d_in[1];
    const float* eps    = (const float*)d_in[2];
    const float* w_ih0  = (const float*)d_in[3];
    const float* w_hh0  = (const float*)d_in[4];
    const float* b_ih0  = (const float*)d_in[5];
    const float* b_hh0  = (const float*)d_in[6];
    const float* w_ih1  = (const float*)d_in[7];
    const float* w_hh1  = (const float*)d_in[8];
    const float* b_ih1  = (const float*)d_in[9];
    const float* b_hh1  = (const float*)d_in[10];
    const float* enc_w1 = (const float*)d_in[11];
    const float* enc_b1 = (const float*)d_in[12];
    const float* enc_a1 = (const float*)d_in[13];
    const float* enc_w2 = (const float*)d_in[14];
    const float* enc_b2 = (const float*)d_in[15];
    const float* enc_a2 = (const float*)d_in[16];
    const float* enc_w3 = (const float*)d_in[17];
    const float* enc_b3 = (const float*)d_in[18];
    const float* dec_w1 = (const float*)d_in[19];
    const float* dec_b1 = (const float*)d_in[20];
    const float* dec_a1 = (const float*)d_in[21];
    const float* dec_w2 = (const float*)d_in[22];
    const float* dec_b2 = (const float*)d_in[23];
    const float* dec_a2 = (const float*)d_in[24];
    const float* dec_w3 = (const float*)d_in[25];
    const float* dec_b3 = (const float*)d_in[26];
    float* out = (float*)d_out;

    omni_anomaly_kernel<<<1, 64, 0, stream>>>(
        x, hidden, eps,
        w_ih0, w_hh0, b_ih0, b_hh0,
        w_ih1, w_hh1, b_ih1, b_hh1,
        enc_w1, enc_b1, enc_a1,
        enc_w2, enc_b2, enc_a2,
        enc_w3, enc_b3,
        dec_w1, dec_b1, dec_a1,
        dec_w2, dec_b2, dec_a2,
        dec_w3, dec_b3,
        out);
}

// Round 3
// 12.363 us; speedup vs baseline: 1.0394x; 1.0394x over previous
//
#include <hip/hip_runtime.h>
#include <math.h>

#define NH 32
#define NL 8
#define NF 128

// Intra-wave scheduling fence: orders LDS write->read across lanes of one
// wave without s_barrier / vmcnt drain (validated in round 2).
#define WSYNC() __builtin_amdgcn_wave_barrier()

__device__ __forceinline__ float sigmoidf_(float x) {
    return 1.0f / (1.0f + __expf(-x));
}
__device__ __forceinline__ float tanhf_(float x) {
    float e = __expf(2.0f * x);
    return 1.0f - 2.0f / (e + 1.0f);
}
__device__ __forceinline__ float preluf_(float x, float a) {
    return x >= 0.0f ? x : a * x;
}

// Streaming dot: weights from global, s-vector from LDS (broadcast reads).
// Partial unroll keeps <=8 float4 loads in flight (bounds VGPR pressure).
__device__ __forceinline__ float dotG32(const float* __restrict__ w, const float* s) {
    const float4* w4 = (const float4*)w;
    float a0 = 0.f, a1 = 0.f, a2 = 0.f, a3 = 0.f;
#pragma unroll 8
    for (int i = 0; i < 32; ++i) {
        float4 a = w4[i];
        a0 = fmaf(a.x, s[4 * i + 0], a0);
        a1 = fmaf(a.y, s[4 * i + 1], a1);
        a2 = fmaf(a.z, s[4 * i + 2], a2);
        a3 = fmaf(a.w, s[4 * i + 3], a3);
    }
    return (a0 + a1) + (a2 + a3);
}
__device__ __forceinline__ float dotG8(const float* __restrict__ w, const float* s) {
    const float4* w4 = (const float4*)w;
    float a0 = 0.f, a1 = 0.f, a2 = 0.f, a3 = 0.f;
#pragma unroll
    for (int i = 0; i < 8; ++i) {
        float4 a = w4[i];
        a0 = fmaf(a.x, s[4 * i + 0], a0);
        a1 = fmaf(a.y, s[4 * i + 1], a1);
        a2 = fmaf(a.z, s[4 * i + 2], a2);
        a3 = fmaf(a.w, s[4 * i + 3], a3);
    }
    return (a0 + a1) + (a2 + a3);
}

// Register-resident weight dot vs LDS vector (broadcast). N4 compile-time.
template <int N4>
__device__ __forceinline__ float dotR(const float4* w, const float* s) {
    float a0 = 0.f, a1 = 0.f, a2 = 0.f, a3 = 0.f;
#pragma unroll
    for (int i = 0; i < N4; ++i) {
        float4 a = w[i];
        a0 = fmaf(a.x, s[4 * i + 0], a0);
        a1 = fmaf(a.y, s[4 * i + 1], a1);
        a2 = fmaf(a.z, s[4 * i + 2], a2);
        a3 = fmaf(a.w, s[4 * i + 3], a3);
    }
    return (a0 + a1) + (a2 + a3);
}

__global__ void __launch_bounds__(128)
omni_anomaly_kernel(const float* __restrict__ x,
                    const float* __restrict__ hidden,
                    const float* __restrict__ eps,
                    const float* __restrict__ w_ih0, const float* __restrict__ w_hh0,
                    const float* __restrict__ b_ih0, const float* __restrict__ b_hh0,
                    const float* __restrict__ w_ih1, const float* __restrict__ w_hh1,
                    const float* __restrict__ b_ih1, const float* __restrict__ b_hh1,
                    const float* __restrict__ enc_w1, const float* __restrict__ enc_b1,
                    const float* __restrict__ enc_a1,
                    const float* __restrict__ enc_w2, const float* __restrict__ enc_b2,
                    const float* __restrict__ enc_a2,
                    const float* __restrict__ enc_w3, const float* __restrict__ enc_b3,
                    const float* __restrict__ dec_w1, const float* __restrict__ dec_b1,
                    const float* __restrict__ dec_a1,
                    const float* __restrict__ dec_w2, const float* __restrict__ dec_b2,
                    const float* __restrict__ dec_a2,
                    const float* __restrict__ dec_w3, const float* __restrict__ dec_b3,
                    float* __restrict__ out) {
    // Per-wave copies of x and hidden -> no cross-wave barrier for staging.
    __shared__ __align__(16) float sxA[NF], sxB[NF];
    __shared__ __align__(16) float shA[2 * NH], shB[2 * NH];
    __shared__ __align__(16) float gi0[3 * NH], gh0[3 * NH], gh1[3 * NH];
    __shared__ __align__(16) float h0n[NH], h1n[NH];
    __shared__ __align__(16) float e1b[NH], e2b[NH], eo[2 * NL], zb[NL];
    __shared__ __align__(16) float d1b[NH], d2b[NH];

    const int t = threadIdx.x;          // 0..127, two waves
    const int hr = t & 31;              // row within half-split stages
    const int half = (t >> 5) & 1;      // 0: cols 0-15, 1: cols 16-31 (wave0)

    // ---- per-wave staging (intra-wave sync only) ----
    if (t < 32) {
        ((float4*)sxA)[t] = ((const float4*)x)[t];
    } else if (t < 48) {
        ((float4*)shA)[t - 32] = ((const float4*)hidden)[t - 32];
    } else if (t >= 64 && t < 96) {
        ((float4*)sxB)[t - 64] = ((const float4*)x)[t - 64];
    } else if (t >= 96 && t < 112) {
        ((float4*)shB)[t - 96] = ((const float4*)hidden)[t - 96];
    }
    WSYNC();

    // ---- wave0: prefetch ALL mid-section weights into registers.
    // Issued before the big GRU0 dots; retired during them; consumed after
    // barrier #2 with zero load latency in the serial chain. ----
    float4 wih1a[8], wih1b[8];          // w_ih1 row t / row t+64
    float4 we1[4], we2[4], wd2[4], we3[4], wd1[2];
    float bi1a = 0.f, bi1b = 0.f, be1 = 0.f, be2 = 0.f, be3 = 0.f;
    float bd1 = 0.f, bd2 = 0.f, epsr = 0.f;
    float a_e1 = 0.f, a_e2 = 0.f, a_d1 = 0.f, a_d2 = 0.f;
    if (t < 64) {
        const float4* r = (const float4*)(w_ih1 + t * NH);
#pragma unroll
        for (int i = 0; i < 8; ++i) wih1a[i] = r[i];
        bi1a = b_ih1[t];
        if (t < 32) {
            const float4* r2 = (const float4*)(w_ih1 + (t + 64) * NH);
#pragma unroll
            for (int i = 0; i < 8; ++i) wih1b[i] = r2[i];
            bi1b = b_ih1[t + 64];
        }
        const float4* p1 = (const float4*)(enc_w1 + hr * NH + half * 16);
        const float4* p2 = (const float4*)(enc_w2 + hr * NH + half * 16);
        const float4* p4 = (const float4*)(dec_w2 + hr * NH + half * 16);
#pragma unroll
        for (int i = 0; i < 4; ++i) { we1[i] = p1[i]; we2[i] = p2[i]; wd2[i] = p4[i]; }
        if (hr < 16) {
            const float4* p3 = (const float4*)(enc_w3 + hr * NH + half * 16);
#pragma unroll
            for (int i = 0; i < 4; ++i) we3[i] = p3[i];
        }
        if (half == 0) {
            const float4* p5 = (const float4*)(dec_w1 + hr * NL);
            wd1[0] = p5[0]; wd1[1] = p5[1];
            be1 = enc_b1[hr]; be2 = enc_b2[hr];
            bd1 = dec_b1[hr]; bd2 = dec_b2[hr];
            if (hr < 16) be3 = enc_b3[hr];
            if (hr < 8)  epsr = eps[hr];
        }
        a_e1 = enc_a1[0]; a_e2 = enc_a2[0]; a_d1 = dec_a1[0]; a_d2 = dec_a2[0];
    }
    __builtin_amdgcn_sched_barrier(0);  // pin prefetch issue before the dots

    // ---- phase 2: GRU0 matvecs + gh1 (all 128 lanes) ----
    if (t < 96) {
        const float* sxw = (t < 64) ? sxA : sxB;
        gi0[t] = dotG32(w_ih0 + t * NF, sxw) + b_ih0[t];
    } else {
        int q3 = 3 * (t - 96);
#pragma unroll
        for (int j = 0; j < 3; ++j) {
            gh0[q3 + j] = dotG8(w_hh0 + (q3 + j) * NH, shB) + b_hh0[q3 + j];
            gh1[q3 + j] = dotG8(w_hh1 + (q3 + j) * NH, shB + NH) + b_hh1[q3 + j];
        }
    }
    __syncthreads();  // barrier #2 (drains the prefetch for free)

    if (t < 64) {
        // ---- wave0 serial section: registers + LDS broadcasts only ----
        // GRU0 combine (lanes 0-31)
        if (t < 32) {
            float r = sigmoidf_(gi0[t] + gh0[t]);
            float z = sigmoidf_(gi0[NH + t] + gh0[NH + t]);
            float n = tanhf_(gi0[2 * NH + t] + r * gh0[2 * NH + t]);
            float h = (1.f - z) * n + z * shA[t];
            h0n[t] = h;
            out[NF + 2 * NL + t] = h;           // hidden_new[0]
        }
        WSYNC();
        // gi1 in registers: lane t -> row t; lanes 0-31 also row 64+t
        float g1a = dotR<8>(wih1a, h0n) + bi1a;
        float g1b = 0.f;
        if (t < 32) g1b = dotR<8>(wih1b, h0n) + bi1b;
        int src = (t + 32) & 63;
        float zg = __shfl(g1a, src, 64);        // row 32+t from lane t+32
        // GRU1 combine (lanes 0-31)
        if (t < 32) {
            float r = sigmoidf_(g1a + gh1[t]);
            float z = sigmoidf_(zg + gh1[NH + t]);
            float n = tanhf_(g1b + r * gh1[2 * NH + t]);
            float h = (1.f - z) * n + z * shA[NH + t];
            h1n[t] = h;
            out[NF + 2 * NL + NH + t] = h;      // hidden_new[1]
        }
        WSYNC();
        // encoder 1 (half-split, shfl-combine)
        float p = dotR<4>(we1, h1n + half * 16);
        p += __shfl_xor(p, 32, 64);
        if (half == 0) e1b[hr] = preluf_(p + be1, a_e1);
        WSYNC();
        // encoder 2
        float p2v = dotR<4>(we2, e1b + half * 16);
        p2v += __shfl_xor(p2v, 32, 64);
        if (half == 0) e2b[hr] = preluf_(p2v + be2, a_e2);
        WSYNC();
        // encoder 3 -> mu | logvar (rows 0-15)
        float p3v = dotR<4>(we3, e2b + half * 16);
        p3v += __shfl_xor(p3v, 32, 64);
        if (half == 0 && hr < 16) {
            float v = p3v + be3;
            eo[hr] = v;
            out[NF + hr] = v;                   // mu then logvar
        }
        WSYNC();
        // reparameterize
        if (t < 8) zb[t] = eo[t] + epsr * __expf(0.5f * eo[NL + t]);
        WSYNC();
        // decoder 1 (full 8-wide rows on lanes 0-31)
        if (half == 0) {
            float v = dotR<2>(wd1, zb) + bd1;
            d1b[hr] = preluf_(v, a_d1);
        }
        WSYNC();
        // decoder 2
        float p4v = dotR<4>(wd2, d1b + half * 16);
        p4v += __shfl_xor(p4v, 32, 64);
        if (half == 0) d2b[hr] = preluf_(p4v + bd2, a_d2);
    } else {
        // ---- wave1: prefetch dec_w3 rows while wave0 runs the chain ----
        // (placed here in program order so its registers don't overlap
        //  wave0's mid-section live ranges)
    }
    float4 wd3a[8], wd3b[8];
    float bd3a = 0.f, bd3b = 0.f;
    if (t >= 64) {
        int q = t - 64;
        const float4* p = (const float4*)(dec_w3 + q * NH);
        const float4* p2 = (const float4*)(dec_w3 + (q + 64) * NH);
#pragma unroll
        for (int i = 0; i < 8; ++i) { wd3a[i] = p[i]; wd3b[i] = p2[i]; }
        bd3a = dec_b3[q]; bd3b = dec_b3[q + 64];
    }
    __syncthreads();  // barrier #3: d2b ready; wd3 loads long since landed

    if (t >= 64) {
        int q = t - 64;
        float v0 = dotR<8>(wd3a, d2b) + bd3a;
        float v1 = dotR<8>(wd3b, d2b) + bd3b;
        out[q] = sigmoidf_(v0);
        out[q + 64] = sigmoidf_(v1);
    }
}

extern "C" void kernel_launch(void* const* d_in, const int* in_sizes, int n_in,
                              void* d_out, int out_size, void* d_ws, size_t ws_size,
                              hipStream_t stream) {
    const float* x      = (const float*)d_in[0];
    const float* hidden = (const float*)d_in[1];
    const float* eps    = (const float*)d_in[2];
    const float* w_ih0  = (const float*)d_in[3];
    const float* w_hh0  = (const float*)d_in[4];
    const float* b_ih0  = (const float*)d_in[5];
    const float* b_hh0  = (const float*)d_in[6];
    const float* w_ih1  = (const float*)d_in[7];
    const float* w_hh1  = (const float*)d_in[8];
    const float* b_ih1  = (const float*)d_in[9];
    const float* b_hh1  = (const float*)d_in[10];
    const float* enc_w1 = (const float*)d_in[11];
    const float* enc_b1 = (const float*)d_in[12];
    const float* enc_a1 = (const float*)d_in[13];
    const float* enc_w2 = (const float*)d_in[14];
    const float* enc_b2 = (const float*)d_in[15];
    const float* enc_a2 = (const float*)d_in[16];
    const float* enc_w3 = (const float*)d_in[17];
    const float* enc_b3 = (const float*)d_in[18];
    const float* dec_w1 = (const float*)d_in[19];
    const float* dec_b1 = (const float*)d_in[20];
    const float* dec_a1 = (const float*)d_in[21];
    const float* dec_w2 = (const float*)d_in[22];
    const float* dec_b2 = (const float*)d_in[23];
    const float* dec_a2 = (const float*)d_in[24];
    const float* dec_w3 = (const float*)d_in[25];
    const float* dec_b3 = (const float*)d_in[26];
    float* out = (float*)d_out;

    omni_anomaly_kernel<<<1, 128, 0, stream>>>(
        x, hidden, eps,
        w_ih0, w_hh0, b_ih0, b_hh0,
        w_ih1, w_hh1, b_ih1, b_hh1,
        enc_w1, enc_b1, enc_a1,
        enc_w2, enc_b2, enc_a2,
        enc_w3, enc_b3,
        dec_w1, dec_b1, dec_a1,
        dec_w2, dec_b2, dec_a2,
        dec_w3, dec_b3,
        out);
}